// Round 5
// baseline (392.821 us; speedup 1.0000x reference)
//
#include <hip/hip_runtime.h>

// Problem constants (match reference)
#define C_BINS 9
#define H_IN 180
#define W_IN 240
#define IMG 640
#define NEV 250000
#define BATCH 8
#define NEG_SLOPE 0.1f
#define HW (H_IN * W_IN)                         // 43200
#define NV (2 * C_BINS * HW * BATCH)             // 6,220,800 voxels
#define TN 2048                                  // table intervals (TN+1 nodes over [-1,1])

// native clang vector type — __builtin_nontemporal_store requires it
// (HIP's float4 is a class and is rejected).
typedef float f32x4 __attribute__((ext_vector_type(4)));

// workspace layout (bytes)
#define WS_BMAX_OFF   0            // 8 x i32 (float bits; signed-max trick, no init needed)
#define WS_TABLE_OFF  128          // (TN+1) x f32
#define WS_VOX_OFF    65536        // NV x f32 (16B aligned)

// ---------------- kernel A: fused prep ----------------
// Phase A: zero vox (float4, grid-stride)
// Phase B: per-batch max of t -> signed atomicMax on float bits.
//          0xAA poison = negative as i32; any positive float's bits win -> no memset.
// Phase C: block b computes table node b (one of TN+1), W2 read straight from L2.
__global__ __launch_bounds__(128) void prep_kernel(
        const float* __restrict__ ev,
        const float* __restrict__ W1, const float* __restrict__ b1,
        const float* __restrict__ W2, const float* __restrict__ b2,
        const float* __restrict__ W3, const float* __restrict__ b3,
        int* __restrict__ bmax_i, float* __restrict__ table,
        float4* __restrict__ vox4) {
    int blk = blockIdx.x, tid = threadIdx.x;
    int gtid = blk * 128 + tid;
    int gstride = gridDim.x * 128;

    // A: zero voxel grid
    float4 z = make_float4(0.f, 0.f, 0.f, 0.f);
    for (int i = gtid; i < NV / 4; i += gstride) vox4[i] = z;

    // B: per-batch max of t (t>0 -> int ordering == float ordering)
    __shared__ int smax[BATCH];
    if (tid < BATCH) smax[tid] = 0;
    __syncthreads();
    for (int i = gtid; i < NEV; i += gstride) {
        float t = ev[i * 5 + 2];
        int b = (int)ev[i * 5 + 4];
        atomicMax(&smax[b], __float_as_int(t));
    }
    __syncthreads();
    if (tid < BATCH) atomicMax(&bmax_i[tid], smax[tid]);

    // C: table node `blk`
    __shared__ float h1s[100];
    __shared__ float red[128];
    float s = -1.f + 2.f * (float)blk / (float)TN;
    if (tid < 100) {
        float h = fmaf(s, W1[tid], b1[tid]);
        h1s[tid] = h > 0.f ? h : NEG_SLOPE * h;
    }
    __syncthreads();
    float acc = 0.f;
    if (tid < 100) {
        #pragma unroll 4
        for (int j = 0; j < 100; ++j) acc = fmaf(h1s[j], W2[j * 100 + tid], acc);
        acc += b2[tid];
        acc = acc > 0.f ? acc : NEG_SLOPE * acc;
        acc *= W3[tid];
    }
    red[tid] = tid < 100 ? acc : 0.f;
    __syncthreads();
    for (int off = 64; off > 0; off >>= 1) {
        if (tid < off) red[tid] += red[tid + off];
        __syncthreads();
    }
    if (tid == 0) table[blk] = red[0] + b3[0];
}

// ---------------- kernel B: scatter events into voxel grid ----------------
__global__ void scatter_kernel(const float* __restrict__ ev,
                               const int* __restrict__ bmax_i,
                               const float* __restrict__ table,
                               float* __restrict__ vox) {
    int i = blockIdx.x * blockDim.x + threadIdx.x;
    if (i >= NEV) return;
    float x = ev[i * 5 + 0];
    float y = ev[i * 5 + 1];
    float t = ev[i * 5 + 2];
    float p = ev[i * 5 + 3];
    int   b = (int)ev[i * 5 + 4];
    float tn = t / __int_as_float(bmax_i[b]);
    int base = (int)x + W_IN * (int)y + HW * C_BINS * (int)p + HW * C_BINS * 2 * b;
    float u0 = (tn + 1.f) * (0.5f * (float)TN);
    int k0 = (int)floorf(u0);
    float f = u0 - (float)k0;
    #pragma unroll
    for (int bin = 0; bin < C_BINS; ++bin) {
        int k = k0 - 128 * bin;                  // 128 = (1/8)*(TN/2), exact
        float fb = f;
        if (k >= TN) { k = TN - 1; fb = 1.f; }   // s == 1.0 exactly (the max event)
        if (k < 0)   { k = 0;      fb = 0.f; }   // safety
        float t0 = table[k], t1 = table[k + 1];
        float g = fmaf(t1 - t0, fb, t0);
        int idx = base + HW * bin;
        idx = max(0, min(idx, NV - 1));
        atomicAdd(&vox[idx], tn * g);
    }
}

// ---------------- kernel C: separable resize + letterbox, nontemporal ------
// One block per (plane, 8-output-row tile). Stage <=5 input rows in LDS,
// horizontally pre-interpolate them to 640 wide (separable bilinear), hoist
// per-row vertical weights to LDS, then the store loop is LDS-read + 1 fma +
// nontemporal float4 store (out is never re-read; keep L2 for vox).
__global__ __launch_bounds__(256) void out_kernel3(const float* __restrict__ vox,
                                                   float* __restrict__ out) {
    int bc = blockIdx.x / 80;          // 0..143 plane (b*18 + ch)
    int ty = blockIdx.x % 80;          // 8-row tile
    int oy0 = ty * 8;
    int tid = threadIdx.x;
    f32x4* dst = (f32x4*)(out + ((size_t)bc * IMG + oy0) * IMG);

    if (ty < 10 || ty >= 70) {         // letterbox bars (tile-aligned)
        f32x4 v = {114.f, 114.f, 114.f, 114.f};
        for (int g = tid; g < 1280; g += 256)
            __builtin_nontemporal_store(v, &dst[g]);
        return;
    }

    __shared__ float sm[5][W_IN];      // raw input rows
    __shared__ float hr[5][IMG];       // horizontally interpolated rows
    __shared__ float wyv[8];
    __shared__ int   l0v[8], l1v[8];

    int ry0 = oy0 - 80;
    float sy0 = fmaf((float)ry0 + 0.5f, 0.375f, -0.5f);
    int ybase = (int)floorf(sy0);
    const float* plane = vox + (size_t)bc * HW;

    // stage raw rows
    for (int idx = tid; idx < 5 * W_IN; idx += 256) {
        int r = idx / W_IN, c = idx - r * W_IN;
        int sr = min(max(ybase + r, 0), H_IN - 1);
        sm[r][c] = plane[sr * W_IN + c];
    }
    // vertical weights per output row
    if (tid < 8) {
        int ry = ry0 + tid;
        float sy = fmaf((float)ry + 0.5f, 0.375f, -0.5f);
        int y0 = (int)floorf(sy);
        wyv[tid] = sy - (float)y0;
        l0v[tid] = max(y0, 0) - ybase;
        l1v[tid] = min(y0 + 1, H_IN - 1) - ybase;
    }
    __syncthreads();

    // horizontal pass: 5 rows x 640 cols
    for (int idx = tid; idx < 5 * IMG; idx += 256) {
        int r = idx / IMG, ox = idx - r * IMG;
        float sx = fmaf((float)ox + 0.5f, 0.375f, -0.5f);
        int x0 = (int)floorf(sx);
        float wx = sx - (float)x0;
        int x1 = min(x0 + 1, W_IN - 1);
        x0 = max(x0, 0);
        float a = sm[r][x0];
        hr[r][ox] = fmaf(sm[r][x1] - a, wx, a);
    }
    __syncthreads();

    // store loop: 8 rows x 160 float4 groups
    for (int g = tid; g < 1280; g += 256) {
        int row = g / 160;
        int gx = (g - row * 160) * 4;
        float wy = wyv[row];
        const float* h0 = hr[l0v[row]];
        const float* h1 = hr[l1v[row]];
        f32x4 v;
        v.x = fmaf(h1[gx + 0] - h0[gx + 0], wy, h0[gx + 0]);
        v.y = fmaf(h1[gx + 1] - h0[gx + 1], wy, h0[gx + 1]);
        v.z = fmaf(h1[gx + 2] - h0[gx + 2], wy, h0[gx + 2]);
        v.w = fmaf(h1[gx + 3] - h0[gx + 3], wy, h0[gx + 3]);
        __builtin_nontemporal_store(v, &dst[g]);
    }
}

extern "C" void kernel_launch(void* const* d_in, const int* in_sizes, int n_in,
                              void* d_out, int out_size, void* d_ws, size_t ws_size,
                              hipStream_t stream) {
    const float* ev = (const float*)d_in[0];
    const float* W1 = (const float*)d_in[1];
    const float* b1 = (const float*)d_in[2];
    const float* W2 = (const float*)d_in[3];
    const float* b2 = (const float*)d_in[4];
    const float* W3 = (const float*)d_in[5];
    const float* b3 = (const float*)d_in[6];
    float* out = (float*)d_out;

    char* ws = (char*)d_ws;
    int*    bmax_i = (int*)(ws + WS_BMAX_OFF);
    float*  table  = (float*)(ws + WS_TABLE_OFF);
    float*  vox    = (float*)(ws + WS_VOX_OFF);

    prep_kernel<<<TN + 1, 128, 0, stream>>>(ev, W1, b1, W2, b2, W3, b3,
                                            bmax_i, table, (float4*)vox);
    scatter_kernel<<<(NEV + 255) / 256, 256, 0, stream>>>(ev, bmax_i, table, vox);
    out_kernel3<<<144 * 80, 256, 0, stream>>>(vox, out);
}